// Round 1
// baseline (33.646 us; speedup 1.0000x reference)
//
#include <hip/hip_runtime.h>

#define N_SUB 128

__global__ void didge_kernel(const float* __restrict__ length,
                             const float* __restrict__ d1p,
                             const int* __restrict__ fmin_p,
                             float* __restrict__ out, int out_n) {
    int tid = blockIdx.x * blockDim.x + threadIdx.x;
    if (tid >= out_n) return;

    const double PI = 3.14159265358979323846;
    const double RHO = 1.2929;
    const double C_SOUND = 343.37;

    const double f = (double)fmin_p[0] + (double)tid;
    const double L_m = (double)length[0] * 10.0 / 1000.0;
    const double d1v = (double)d1p[0];
    const double dL = L_m / (double)N_SUB;
    const double k = 2.0 * PI * f / C_SOUND;

    // b = k*dL is segment-independent: hoist sin/cos out of the loop.
    const double b = k * dL;
    const double cb = cos(b);
    const double sb = sin(b);
    const double sqf = sqrt(f);

    // M = identity (complex 2x2 accumulator), M <- M @ T_j, j = 0..127
    double M00r = 1.0, M00i = 0.0, M01r = 0.0, M01i = 0.0;
    double M10r = 0.0, M10i = 0.0, M11r = 1.0, M11i = 0.0;

    #pragma unroll 4
    for (int j = 0; j < N_SUB; ++j) {
        double t = ((double)j + 0.5) / (double)N_SUB;
        double r = (32.0 + (d1v - 32.0) * t) / 2000.0;
        double alpha = 3e-5 * sqf / r;
        double a = alpha * dL;           // |a| <= ~4e-4 for these inputs
        double a2 = a * a;
        // Degree-6 Taylor: exact to double precision for |a| << 0.1
        double cha = 1.0 + a2 * (0.5 + a2 * (1.0/24.0 + a2 * (1.0/720.0)));
        double sha = a * (1.0 + a2 * (1.0/6.0 + a2 * (1.0/120.0 + a2 * (1.0/5040.0))));

        // cosh(a+ib) = cha*cb + i*sha*sb ; sinh(a+ib) = sha*cb + i*cha*sb
        double chr = cha * cb, chi = sha * sb;
        double shr = sha * cb, shi = cha * sb;

        double Z0  = RHO * C_SOUND / (PI * r * r);
        double iZ0 = 1.0 / Z0;
        double T01r = Z0 * shr,  T01i = Z0 * shi;   // Z0 * sh
        double T10r = iZ0 * shr, T10i = iZ0 * shi;  // sh / Z0

        // M = M @ T  where T = [[ch, Z0*sh], [sh/Z0, ch]]
        double n00r = M00r*chr  - M00i*chi  + M01r*T10r - M01i*T10i;
        double n00i = M00r*chi  + M00i*chr  + M01r*T10i + M01i*T10r;
        double n01r = M00r*T01r - M00i*T01i + M01r*chr  - M01i*chi;
        double n01i = M00r*T01i + M00i*T01r + M01r*chi  + M01i*chr;
        double n10r = M10r*chr  - M10i*chi  + M11r*T10r - M11i*T10i;
        double n10i = M10r*chi  + M10i*chr  + M11r*T10i + M11i*T10r;
        double n11r = M10r*T01r - M10i*T01i + M11r*chr  - M11i*chi;
        double n11i = M10r*T01i + M10i*T01r + M11r*chi  + M11i*chr;
        M00r = n00r; M00i = n00i; M01r = n01r; M01i = n01i;
        M10r = n10r; M10i = n10i; M11r = n11r; M11i = n11i;
    }

    // Radiation load ZL = Z0_end * (0.25*(kr)^2 + i*0.61*kr)
    double r_end = d1v / 2000.0;
    double Z0e = RHO * C_SOUND / (PI * r_end * r_end);
    double kr = k * r_end;
    double ZLr = Z0e * 0.25 * kr * kr;
    double ZLi = Z0e * 0.61 * kr;

    // Ze = (A*ZL + B) / (C*ZL + D);  |Ze| = |num| / |den|
    double numr = M00r*ZLr - M00i*ZLi + M01r;
    double numi = M00r*ZLi + M00i*ZLr + M01i;
    double denr = M10r*ZLr - M10i*ZLi + M11r;
    double deni = M10r*ZLi + M10i*ZLr + M11i;

    double mag = sqrt((numr*numr + numi*numi) / (denr*denr + deni*deni));
    out[tid] = (float)mag;
}

extern "C" void kernel_launch(void* const* d_in, const int* in_sizes, int n_in,
                              void* d_out, int out_size, void* d_ws, size_t ws_size,
                              hipStream_t stream) {
    const float* length = (const float*)d_in[0];
    const float* d1     = (const float*)d_in[1];
    const int*   fmin   = (const int*)d_in[2];
    float* out = (float*)d_out;

    int block = 64;
    int grid = (out_size + block - 1) / block;
    didge_kernel<<<grid, block, 0, stream>>>(length, d1, fmin, out, out_size);
}

// Round 2
// 10.163 us; speedup vs baseline: 3.3108x; 3.3108x over previous
//
#include <hip/hip_runtime.h>

#define N_SUB 128

struct CM { double r00,i00,r01,i01,r10,i10,r11,i11; };

// C = A @ B (complex 2x2)
__device__ inline CM cmm(const CM& A, const CM& B) {
    CM C;
    C.r00 = A.r00*B.r00 - A.i00*B.i00 + A.r01*B.r10 - A.i01*B.i10;
    C.i00 = A.r00*B.i00 + A.i00*B.r00 + A.r01*B.i10 + A.i01*B.r10;
    C.r01 = A.r00*B.r01 - A.i00*B.i01 + A.r01*B.r11 - A.i01*B.i11;
    C.i01 = A.r00*B.i01 + A.i00*B.r01 + A.r01*B.i11 + A.i01*B.r11;
    C.r10 = A.r10*B.r00 - A.i10*B.i00 + A.r11*B.r10 - A.i11*B.i10;
    C.i10 = A.r10*B.i00 + A.i10*B.r00 + A.r11*B.i10 + A.i11*B.r10;
    C.r11 = A.r10*B.r01 - A.i10*B.i01 + A.r11*B.r11 - A.i11*B.i11;
    C.i11 = A.r10*B.i01 + A.i10*B.r01 + A.r11*B.i11 + A.i11*B.r11;
    return C;
}

__device__ inline CM shfl_xor_cm(const CM& P, int mask) {
    CM Q;
    Q.r00 = __shfl_xor(P.r00, mask, 64); Q.i00 = __shfl_xor(P.i00, mask, 64);
    Q.r01 = __shfl_xor(P.r01, mask, 64); Q.i01 = __shfl_xor(P.i01, mask, 64);
    Q.r10 = __shfl_xor(P.r10, mask, 64); Q.i10 = __shfl_xor(P.i10, mask, 64);
    Q.r11 = __shfl_xor(P.r11, mask, 64); Q.i11 = __shfl_xor(P.i11, mask, 64);
    return Q;
}

__device__ inline CM buildT(int j, double d1v, double sqf, double dL,
                            double cb, double sb) {
    const double PI  = 3.14159265358979323846;
    const double C1  = 1.2929 * 343.37 / PI;   // RHO*C/pi
    const double IC1 = PI / (1.2929 * 343.37); // pi/(RHO*C)

    double t = ((double)j + 0.5) * (1.0 / (double)N_SUB);
    double r = (32.0 + (d1v - 32.0) * t) * (1.0 / 2000.0);
    double rinv = 1.0 / r;
    double a = 3e-5 * sqf * rinv * dL;         // alpha*dL, |a| << 1e-3
    double a2 = a * a;
    // Taylor for cosh/sinh of the tiny real part: exact to f64 here
    double cha = 1.0 + a2 * (0.5 + a2 * (1.0/24.0 + a2 * (1.0/720.0)));
    double sha = a * (1.0 + a2 * (1.0/6.0 + a2 * (1.0/120.0 + a2 * (1.0/5040.0))));

    // cosh(a+ib) = cha*cb + i*sha*sb ; sinh(a+ib) = sha*cb + i*cha*sb
    double chr = cha * cb, chi = sha * sb;
    double shr = sha * cb, shi = cha * sb;

    double Z0  = C1 * rinv * rinv;
    double iZ0 = r * r * IC1;

    CM T;
    T.r00 = chr;       T.i00 = chi;
    T.r01 = Z0 * shr;  T.i01 = Z0 * shi;
    T.r10 = iZ0 * shr; T.i10 = iZ0 * shi;
    T.r11 = chr;       T.i11 = chi;
    return T;
}

// One wave (64 lanes) per frequency; lane l owns segments 2l, 2l+1;
// 6-level ordered butterfly product across the wave.
__global__ void didge_kernel(const float* __restrict__ length,
                             const float* __restrict__ d1p,
                             const int* __restrict__ fmin_p,
                             float* __restrict__ out, int out_n) {
    int gtid = blockIdx.x * blockDim.x + threadIdx.x;
    int wave = gtid >> 6;       // one frequency per wave
    int lane = gtid & 63;
    if (wave >= out_n) return;  // wave-uniform exit

    const double PI = 3.14159265358979323846;
    const double C_SOUND = 343.37;
    const double C1 = 1.2929 * C_SOUND / PI;

    const double f   = (double)fmin_p[0] + (double)wave;
    const double L_m = (double)length[0] * 10.0 / 1000.0;
    const double d1v = (double)d1p[0];
    const double dL  = L_m / (double)N_SUB;
    const double k   = 2.0 * PI * f / C_SOUND;

    const double b  = k * dL;   // segment-independent imaginary part
    const double cb = cos(b);
    const double sb = sin(b);
    const double sqf = sqrt(f);

    // Per-lane pair product: P = T_{2l} @ T_{2l+1}
    CM P = cmm(buildT(2*lane,     d1v, sqf, dL, cb, sb),
               buildT(2*lane + 1, d1v, sqf, dL, cb, sb));

    // Ordered tree: after level s, every lane in an aligned 2^(s+1) group
    // holds that group's full left-to-right product.
    #pragma unroll
    for (int s = 0; s < 6; ++s) {
        int m = 1 << s;
        CM Q = shfl_xor_cm(P, m);
        bool left = (lane & m) == 0;      // our group is the left operand?
        CM Lm, Rm;
        Lm.r00 = left ? P.r00 : Q.r00; Lm.i00 = left ? P.i00 : Q.i00;
        Lm.r01 = left ? P.r01 : Q.r01; Lm.i01 = left ? P.i01 : Q.i01;
        Lm.r10 = left ? P.r10 : Q.r10; Lm.i10 = left ? P.i10 : Q.i10;
        Lm.r11 = left ? P.r11 : Q.r11; Lm.i11 = left ? P.i11 : Q.i11;
        Rm.r00 = left ? Q.r00 : P.r00; Rm.i00 = left ? Q.i00 : P.i00;
        Rm.r01 = left ? Q.r01 : P.r01; Rm.i01 = left ? Q.i01 : P.i01;
        Rm.r10 = left ? Q.r10 : P.r10; Rm.i10 = left ? Q.i10 : P.i10;
        Rm.r11 = left ? Q.r11 : P.r11; Rm.i11 = left ? Q.i11 : P.i11;
        P = cmm(Lm, Rm);
    }

    if (lane == 0) {
        double r_end = d1v / 2000.0;
        double Z0e = C1 / (r_end * r_end);
        double kr = k * r_end;
        double ZLr = Z0e * 0.25 * kr * kr;
        double ZLi = Z0e * 0.61 * kr;

        double numr = P.r00*ZLr - P.i00*ZLi + P.r01;
        double numi = P.r00*ZLi + P.i00*ZLr + P.i01;
        double denr = P.r10*ZLr - P.i10*ZLi + P.r11;
        double deni = P.r10*ZLi + P.i10*ZLr + P.i11;

        out[wave] = (float)sqrt((numr*numr + numi*numi) /
                                (denr*denr + deni*deni));
    }
}

extern "C" void kernel_launch(void* const* d_in, const int* in_sizes, int n_in,
                              void* d_out, int out_size, void* d_ws, size_t ws_size,
                              hipStream_t stream) {
    const float* length = (const float*)d_in[0];
    const float* d1     = (const float*)d_in[1];
    const int*   fmin   = (const int*)d_in[2];
    float* out = (float*)d_out;

    int block = 256;                               // 4 waves = 4 frequencies/block
    int waves_needed = out_size;
    int grid = (waves_needed * 64 + block - 1) / block;
    didge_kernel<<<grid, block, 0, stream>>>(length, d1, fmin, out, out_size);
}